// Round 1
// baseline (443.081 us; speedup 1.0000x reference)
//
#include <hip/hip_runtime.h>

// GCN_4492535792198: 3-layer GCN forward on MI355X.
// N=50000 nodes, E=800000 edges, D_IN=D_HID=128, N_CLASSES=64.
// Outputs (concat in d_out): logp [N,64], e1 [N,128], e2 [N,128], e3 [N,64].

// ---------------- edge_index dtype detection (int32 vs int64) ----------------
// If the buffer is int64, every value is in [0, 50000) so the high 32 bits of
// the first 64 int64 slots are all zero. If it is int32, those "high words"
// are dst-row values (random in [0,50000)) - virtually impossible to all be 0.
__global__ void detect_dtype_kernel(const void* ei, int* flag) {
    int lane = threadIdx.x;                       // 64 threads
    long long v = ((const long long*)ei)[lane];
    int bad = (v < 0 || v >= (1LL << 32)) ? 1 : 0;
    unsigned long long m = __ballot(bad);
    if (lane == 0) *flag = (m == 0ULL) ? 1 : 0;   // 1 => int64
}

__device__ __forceinline__ int edge_at(const void* ei, int is64, long long i) {
    if (is64) return (int)((const long long*)ei)[i];
    return ((const int*)ei)[i];
}

// ---------------- CSR build ----------------
__global__ void zero2_kernel(int* a, int* b, int n) {
    int i = blockIdx.x * blockDim.x + threadIdx.x;
    if (i < n) { a[i] = 0; b[i] = 0; }
}

__global__ void hist_kernel(const void* ei, const int* __restrict__ flag,
                            int* __restrict__ cnt, int E) {
    int e = blockIdx.x * blockDim.x + threadIdx.x;
    if (e >= E) return;
    int is64 = flag[0];
    int d = edge_at(ei, is64, (long long)E + e);
    atomicAdd(&cnt[d], 1);
}

__global__ void dinv_kernel(const int* __restrict__ cnt, float* __restrict__ dinv, int n) {
    int i = blockIdx.x * blockDim.x + threadIdx.x;
    if (i < n) dinv[i] = rsqrtf((float)(cnt[i] + 1));   // +1 self loop; deg>=1 always
}

// block-level exclusive scan (1024 threads/block), emits per-block totals
__global__ void scan1_kernel(const int* __restrict__ cnt, int* __restrict__ rowptr,
                             int* __restrict__ bsum, int n) {
    int tid = threadIdx.x;
    int gid = blockIdx.x * 1024 + tid;
    int v = (gid < n) ? cnt[gid] : 0;
    int lane = tid & 63, wid = tid >> 6;
    int x = v;
#pragma unroll
    for (int off = 1; off < 64; off <<= 1) {
        int t = __shfl_up(x, off, 64);
        if (lane >= off) x += t;
    }
    __shared__ int wsum[16];
    if (lane == 63) wsum[wid] = x;
    __syncthreads();
    if (tid < 64) {
        int y = (lane < 16) ? wsum[lane] : 0;
#pragma unroll
        for (int off = 1; off < 16; off <<= 1) {
            int t = __shfl_up(y, off, 64);
            if (lane >= off) y += t;
        }
        if (lane < 16) wsum[lane] = y;
    }
    __syncthreads();
    int woff = (wid > 0) ? wsum[wid - 1] : 0;
    int incl = x + woff;
    if (gid < n) rowptr[gid] = incl - v;     // block-local exclusive
    if (tid == 1023) bsum[blockIdx.x] = incl;
}

// scan the block totals (single wave, carry loop), write rowptr[n]=E
__global__ void scan2_kernel(const int* __restrict__ bsum, int* __restrict__ boff,
                             int nb, int* __restrict__ rowptr, int n, int E) {
    int lane = threadIdx.x;   // 64 threads
    int carry = 0;
    for (int base = 0; base < nb; base += 64) {
        int idx = base + lane;
        int v = (idx < nb) ? bsum[idx] : 0;
        int x = v;
#pragma unroll
        for (int off = 1; off < 64; off <<= 1) {
            int t = __shfl_up(x, off, 64);
            if (lane >= off) x += t;
        }
        if (idx < nb) boff[idx] = carry + x - v;
        carry += __shfl(x, 63, 64);
    }
    if (lane == 0) rowptr[n] = E;
}

__global__ void scan3_kernel(int* __restrict__ rowptr, const int* __restrict__ boff, int n) {
    int i = blockIdx.x * blockDim.x + threadIdx.x;
    if (i < n) rowptr[i] += boff[i >> 10];
}

__global__ void fill_kernel(const void* ei, const int* __restrict__ flag,
                            const int* __restrict__ rowptr, int* __restrict__ fillc,
                            int* __restrict__ col, int E) {
    int e = blockIdx.x * blockDim.x + threadIdx.x;
    if (e >= E) return;
    int is64 = flag[0];
    int s = edge_at(ei, is64, e);
    int d = edge_at(ei, is64, (long long)E + e);
    int p = rowptr[d] + atomicAdd(&fillc[d], 1);
    col[p] = s;
}

// ---------------- GEMM: out[M,Dout] = act(A[M,128]) @ W[128,Dout] ----------------
// 64x64 tile per 256-thread block, 4x4 micro-tile per thread, K staged in 2x64.
__global__ __launch_bounds__(256) void gemm_kernel(
    const float* __restrict__ A, const float* __restrict__ W,
    float* __restrict__ out, int M, int Dout, int act) {
    __shared__ float As[64 * 65];   // [k][m], stride 65 (conflict-free reads)
    __shared__ float Bs[64 * 64];   // [k][n]
    int tid = threadIdx.x;
    int r0 = blockIdx.x * 64;
    int n0 = blockIdx.y * 64;
    int ty = tid >> 4, tx = tid & 15;

    float acc[4][4];
#pragma unroll
    for (int i = 0; i < 4; ++i)
#pragma unroll
        for (int j = 0; j < 4; ++j) acc[i][j] = 0.f;

    for (int kt = 0; kt < 2; ++kt) {
        // stage A chunk: 64 rows x 64 k   (transpose into As[k][m])
#pragma unroll
        for (int i = 0; i < 4; ++i) {
            int li = tid + i * 256;          // 0..1023
            int row = li >> 4, c4 = li & 15;
            float4 v = make_float4(0.f, 0.f, 0.f, 0.f);
            int gr = r0 + row;
            if (gr < M) v = ((const float4*)(A + (size_t)gr * 128 + kt * 64))[c4];
            if (act) {
                v.x = fmaxf(v.x, 0.f); v.y = fmaxf(v.y, 0.f);
                v.z = fmaxf(v.z, 0.f); v.w = fmaxf(v.w, 0.f);
            }
            int k = c4 * 4;
            As[(k + 0) * 65 + row] = v.x;
            As[(k + 1) * 65 + row] = v.y;
            As[(k + 2) * 65 + row] = v.z;
            As[(k + 3) * 65 + row] = v.w;
        }
        // stage B chunk: 64 k x 64 n
#pragma unroll
        for (int i = 0; i < 4; ++i) {
            int li = tid + i * 256;
            int kk = li >> 4, c4 = li & 15;
            float4 v = ((const float4*)(W + (size_t)(kt * 64 + kk) * Dout + n0))[c4];
            ((float4*)(Bs + kk * 64))[c4] = v;
        }
        __syncthreads();
#pragma unroll 8
        for (int k = 0; k < 64; ++k) {
            float a0 = As[k * 65 + ty * 4 + 0];
            float a1 = As[k * 65 + ty * 4 + 1];
            float a2 = As[k * 65 + ty * 4 + 2];
            float a3 = As[k * 65 + ty * 4 + 3];
            float4 b = ((const float4*)(Bs + k * 64))[tx];
            acc[0][0] += a0 * b.x; acc[0][1] += a0 * b.y; acc[0][2] += a0 * b.z; acc[0][3] += a0 * b.w;
            acc[1][0] += a1 * b.x; acc[1][1] += a1 * b.y; acc[1][2] += a1 * b.z; acc[1][3] += a1 * b.w;
            acc[2][0] += a2 * b.x; acc[2][1] += a2 * b.y; acc[2][2] += a2 * b.z; acc[2][3] += a2 * b.w;
            acc[3][0] += a3 * b.x; acc[3][1] += a3 * b.y; acc[3][2] += a3 * b.z; acc[3][3] += a3 * b.w;
        }
        __syncthreads();
    }
#pragma unroll
    for (int i = 0; i < 4; ++i) {
        int gr = r0 + ty * 4 + i;
        if (gr < M) {
            float4 o = make_float4(acc[i][0], acc[i][1], acc[i][2], acc[i][3]);
            ((float4*)(out + (size_t)gr * Dout + n0))[tx] = o;
        }
    }
}

// ---------------- aggregation: out[i] = di*(sum dinv[s]*xw[s]) + di^2*xw[i] + b ----------------
template <int TPN>   // threads per node = Dout/4
__global__ __launch_bounds__(256) void agg_kernel(
    const float* __restrict__ xw, const float* __restrict__ dinv,
    const int* __restrict__ rowptr, const int* __restrict__ col,
    const float* __restrict__ bias, float* __restrict__ out, int n) {
    int tid = threadIdx.x;
    const int gpb = 256 / TPN;
    int node = blockIdx.x * gpb + tid / TPN;
    int j = tid % TPN;
    if (node >= n) return;
    const float4* xw4 = (const float4*)xw;
    float di = dinv[node];
    int p0 = rowptr[node], p1 = rowptr[node + 1];
    float4 acc = make_float4(0.f, 0.f, 0.f, 0.f);
    for (int p = p0; p < p1; ++p) {
        int s = col[p];
        float w = dinv[s];
        float4 v = xw4[(size_t)s * TPN + j];
        acc.x += w * v.x; acc.y += w * v.y; acc.z += w * v.z; acc.w += w * v.w;
    }
    float4 self = xw4[(size_t)node * TPN + j];
    float4 b = ((const float4*)bias)[j];
    float dii = di * di;
    acc.x = di * acc.x + dii * self.x + b.x;
    acc.y = di * acc.y + dii * self.y + b.y;
    acc.z = di * acc.z + dii * self.z + b.z;
    acc.w = di * acc.w + dii * self.w + b.w;
    ((float4*)out)[(size_t)node * TPN + j] = acc;
}

// ---------------- log_softmax over 64 classes: one wave per row ----------------
__global__ __launch_bounds__(256) void lsm_kernel(const float* __restrict__ e3,
                                                  float* __restrict__ logp, int n) {
    int row = blockIdx.x * 4 + (threadIdx.x >> 6);
    int lane = threadIdx.x & 63;
    if (row >= n) return;
    float v = e3[(size_t)row * 64 + lane];
    float m = v;
#pragma unroll
    for (int off = 32; off >= 1; off >>= 1) m = fmaxf(m, __shfl_xor(m, off, 64));
    float s = expf(v - m);
#pragma unroll
    for (int off = 32; off >= 1; off >>= 1) s += __shfl_xor(s, off, 64);
    logp[(size_t)row * 64 + lane] = v - m - logf(s);
}

// ---------------- driver ----------------
extern "C" void kernel_launch(void* const* d_in, const int* in_sizes, int n_in,
                              void* d_out, int out_size, void* d_ws, size_t ws_size,
                              hipStream_t stream) {
    const float* x  = (const float*)d_in[0];
    const void*  ei = d_in[1];
    const float* W1 = (const float*)d_in[2];
    const float* b1 = (const float*)d_in[3];
    const float* W2 = (const float*)d_in[4];
    const float* b2 = (const float*)d_in[5];
    const float* W3 = (const float*)d_in[6];
    const float* b3 = (const float*)d_in[7];
    float* out = (float*)d_out;

    const int N = in_sizes[0] / 128;   // 50000
    const int E = in_sizes[1] / 2;     // 800000

    // workspace carve (256B aligned); total ~29.7 MB
    char* w = (char*)d_ws;
    size_t off = 0;
    auto alloc = [&](size_t bytes) -> void* {
        void* p = w + off;
        off = (off + bytes + 255) & ~(size_t)255;
        return p;
    };
    int*   flag   = (int*)alloc(4);
    int*   cnt    = (int*)alloc((size_t)N * 4);
    int*   fillc  = (int*)alloc((size_t)N * 4);
    int*   rowptr = (int*)alloc((size_t)(N + 1) * 4);
    int*   bsum   = (int*)alloc(4096);
    int*   boff   = (int*)alloc(4096);
    float* dinv   = (float*)alloc((size_t)N * 4);
    int*   col    = (int*)alloc((size_t)E * 4);
    float* xw     = (float*)alloc((size_t)N * 128 * 4);

    float* logp = out;
    float* e1 = out + (size_t)N * 64;
    float* e2 = e1 + (size_t)N * 128;
    float* e3 = e2 + (size_t)N * 128;

    const int nb = (N + 1023) / 1024;

    detect_dtype_kernel<<<1, 64, 0, stream>>>(ei, flag);
    zero2_kernel<<<(N + 255) / 256, 256, 0, stream>>>(cnt, fillc, N);
    hist_kernel<<<(E + 255) / 256, 256, 0, stream>>>(ei, flag, cnt, E);
    dinv_kernel<<<(N + 255) / 256, 256, 0, stream>>>(cnt, dinv, N);
    scan1_kernel<<<nb, 1024, 0, stream>>>(cnt, rowptr, bsum, N);
    scan2_kernel<<<1, 64, 0, stream>>>(bsum, boff, nb, rowptr, N, E);
    scan3_kernel<<<(N + 255) / 256, 256, 0, stream>>>(rowptr, boff, N);
    fill_kernel<<<(E + 255) / 256, 256, 0, stream>>>(ei, flag, rowptr, fillc, col, E);

    // layer 1
    gemm_kernel<<<dim3((N + 63) / 64, 2), 256, 0, stream>>>(x, W1, xw, N, 128, 0);
    agg_kernel<32><<<(N + 7) / 8, 256, 0, stream>>>(xw, dinv, rowptr, col, b1, e1, N);
    // layer 2 (ReLU applied on load)
    gemm_kernel<<<dim3((N + 63) / 64, 2), 256, 0, stream>>>(e1, W2, xw, N, 128, 1);
    agg_kernel<32><<<(N + 7) / 8, 256, 0, stream>>>(xw, dinv, rowptr, col, b2, e2, N);
    // layer 3 (Dout=64)
    gemm_kernel<<<dim3((N + 63) / 64, 1), 256, 0, stream>>>(e2, W3, xw, N, 64, 1);
    agg_kernel<16><<<(N + 15) / 16, 256, 0, stream>>>(xw, dinv, rowptr, col, b3, e3, N);
    // log_softmax
    lsm_kernel<<<(N + 3) / 4, 256, 0, stream>>>(e3, logp, N);
}

// Round 2
// 319.928 us; speedup vs baseline: 1.3849x; 1.3849x over previous
//
#include <hip/hip_runtime.h>

// GCN_4492535792198: 3-layer GCN forward on MI355X (gfx950).
// N=50000, E=800000, D: 128->128->64. Outputs: logp[N,64], e1[N,128], e2[N,128], e3[N,64].
// R2: bf16 MFMA GEMM (writes xw in bf16) + bf16 gather aggregation with 4-deep MLP unroll.

typedef __attribute__((ext_vector_type(8))) short short8;   // 8 x bf16 (4 VGPRs)
typedef __attribute__((ext_vector_type(4))) float f32x4;

__device__ __forceinline__ ushort f2bf(float f) {
    union { float f; unsigned u; } a; a.f = f;
    unsigned r = a.u + 0x7fffu + ((a.u >> 16) & 1u);   // RNE (finite data)
    return (ushort)(r >> 16);
}
__device__ __forceinline__ float bflo(unsigned u) { return __uint_as_float(u << 16); }
__device__ __forceinline__ float bfhi(unsigned u) { return __uint_as_float(u & 0xffff0000u); }

// ---------------- edge_index dtype detection (int32 vs int64) ----------------
__global__ void detect_dtype_kernel(const void* ei, int* flag) {
    int lane = threadIdx.x;                       // 64 threads
    long long v = ((const long long*)ei)[lane];
    int bad = (v < 0 || v >= (1LL << 32)) ? 1 : 0;
    unsigned long long m = __ballot(bad);
    if (lane == 0) *flag = (m == 0ULL) ? 1 : 0;   // 1 => int64
}

__device__ __forceinline__ int edge_at(const void* ei, int is64, long long i) {
    if (is64) return (int)((const long long*)ei)[i];
    return ((const int*)ei)[i];
}

// ---------------- CSR build ----------------
__global__ void zero2_kernel(int* a, int* b, int n) {
    int i = blockIdx.x * blockDim.x + threadIdx.x;
    if (i < n) { a[i] = 0; b[i] = 0; }
}

__global__ void hist_kernel(const void* ei, const int* __restrict__ flag,
                            int* __restrict__ cnt, int E) {
    int e = blockIdx.x * blockDim.x + threadIdx.x;
    if (e >= E) return;
    int is64 = flag[0];
    int d = edge_at(ei, is64, (long long)E + e);
    atomicAdd(&cnt[d], 1);
}

__global__ void dinv_kernel(const int* __restrict__ cnt, float* __restrict__ dinv, int n) {
    int i = blockIdx.x * blockDim.x + threadIdx.x;
    if (i < n) dinv[i] = rsqrtf((float)(cnt[i] + 1));   // +1 self loop
}

__global__ void scan1_kernel(const int* __restrict__ cnt, int* __restrict__ rowptr,
                             int* __restrict__ bsum, int n) {
    int tid = threadIdx.x;
    int gid = blockIdx.x * 1024 + tid;
    int v = (gid < n) ? cnt[gid] : 0;
    int lane = tid & 63, wid = tid >> 6;
    int x = v;
#pragma unroll
    for (int off = 1; off < 64; off <<= 1) {
        int t = __shfl_up(x, off, 64);
        if (lane >= off) x += t;
    }
    __shared__ int wsum[16];
    if (lane == 63) wsum[wid] = x;
    __syncthreads();
    if (tid < 64) {
        int y = (lane < 16) ? wsum[lane] : 0;
#pragma unroll
        for (int off = 1; off < 16; off <<= 1) {
            int t = __shfl_up(y, off, 64);
            if (lane >= off) y += t;
        }
        if (lane < 16) wsum[lane] = y;
    }
    __syncthreads();
    int woff = (wid > 0) ? wsum[wid - 1] : 0;
    int incl = x + woff;
    if (gid < n) rowptr[gid] = incl - v;
    if (tid == 1023) bsum[blockIdx.x] = incl;
}

__global__ void scan2_kernel(const int* __restrict__ bsum, int* __restrict__ boff,
                             int nb, int* __restrict__ rowptr, int n, int E) {
    int lane = threadIdx.x;   // 64 threads
    int carry = 0;
    for (int base = 0; base < nb; base += 64) {
        int idx = base + lane;
        int v = (idx < nb) ? bsum[idx] : 0;
        int x = v;
#pragma unroll
        for (int off = 1; off < 64; off <<= 1) {
            int t = __shfl_up(x, off, 64);
            if (lane >= off) x += t;
        }
        if (idx < nb) boff[idx] = carry + x - v;
        carry += __shfl(x, 63, 64);
    }
    if (lane == 0) rowptr[n] = E;
}

__global__ void scan3_kernel(int* __restrict__ rowptr, const int* __restrict__ boff, int n) {
    int i = blockIdx.x * blockDim.x + threadIdx.x;
    if (i < n) rowptr[i] += boff[i >> 10];
}

__global__ void fill_kernel(const void* ei, const int* __restrict__ flag,
                            const int* __restrict__ rowptr, int* __restrict__ fillc,
                            int* __restrict__ col, int E) {
    int e = blockIdx.x * blockDim.x + threadIdx.x;
    if (e >= E) return;
    int is64 = flag[0];
    int s = edge_at(ei, is64, e);
    int d = edge_at(ei, is64, (long long)E + e);
    int p = rowptr[d] + atomicAdd(&fillc[d], 1);
    col[p] = s;
}

// ---------------- weight prep: Wt[n][k] = bf16(W[k][n]) ----------------
__global__ void wprep_kernel(const float* __restrict__ W1, const float* __restrict__ W2,
                             const float* __restrict__ W3, ushort* __restrict__ Wt1,
                             ushort* __restrict__ Wt2, ushort* __restrict__ Wt3) {
    int i = blockIdx.x * 256 + threadIdx.x;
    if (i < 16384) {
        int n = i >> 7, k = i & 127;
        Wt1[i] = f2bf(W1[k * 128 + n]);
    } else if (i < 32768) {
        int j = i - 16384; int n = j >> 7, k = j & 127;
        Wt2[j] = f2bf(W2[k * 128 + n]);
    } else if (i < 40960) {
        int j = i - 32768; int n = j >> 7, k = j & 127;
        Wt3[j] = f2bf(W3[k * 64 + n]);
    }
}

// ---------------- MFMA GEMM: xw[M,DOUT](bf16) = relu?(A[M,128]) @ W ----------------
// 128-row x DOUT-col tile per 256-thread block (4 waves x 32 rows).
// LDS stride 136 bf16 (272 B): b128 fragment reads are perfectly bank-balanced.
template <int DOUT>
__global__ __launch_bounds__(256) void mfma_gemm_kernel(
    const float* __restrict__ A, const ushort* __restrict__ Wt,
    ushort* __restrict__ xw, int M, int act) {
    constexpr int NT = DOUT / 16;
    __shared__ ushort As[128 * 136];
    __shared__ ushort Ws[DOUT * 136];
    const int tid = threadIdx.x;
    const int r0 = blockIdx.x * 128;
    const int wid = tid >> 6;
    const int lane = tid & 63;
    const int m = lane & 15, quad = lane >> 4;

    // stage A: fp32 -> (relu) -> bf16, [row][k]
#pragma unroll
    for (int i = 0; i < 16; ++i) {
        int li = tid + i * 256;             // 0..4095 float4 slots
        int row = li >> 5, c4 = li & 31;
        float4 v = make_float4(0.f, 0.f, 0.f, 0.f);
        int gr = r0 + row;
        if (gr < M) v = ((const float4*)(A + (size_t)gr * 128))[c4];
        if (act) {
            v.x = fmaxf(v.x, 0.f); v.y = fmaxf(v.y, 0.f);
            v.z = fmaxf(v.z, 0.f); v.w = fmaxf(v.w, 0.f);
        }
        ushort4 u;
        u.x = f2bf(v.x); u.y = f2bf(v.y); u.z = f2bf(v.z); u.w = f2bf(v.w);
        *(ushort4*)&As[row * 136 + c4 * 4] = u;
    }
    // stage Wt: [n][k] bf16, contiguous 16B chunks
#pragma unroll
    for (int i = 0; i < DOUT / 16; ++i) {
        int li = tid + i * 256;             // uint4 slots over DOUT*16
        int n = li >> 4, c = li & 15;
        uint4 v = ((const uint4*)Wt)[li];
        *(uint4*)&Ws[n * 136 + c * 8] = v;
    }
    __syncthreads();

    f32x4 acc[2][NT];
#pragma unroll
    for (int rt = 0; rt < 2; ++rt)
#pragma unroll
        for (int nt = 0; nt < NT; ++nt) acc[rt][nt] = (f32x4){0.f, 0.f, 0.f, 0.f};

#pragma unroll
    for (int kt = 0; kt < 4; ++kt) {
        const int ko = kt * 32 + quad * 8;
        short8 af0 = *(const short8*)&As[(wid * 32 + m) * 136 + ko];
        short8 af1 = *(const short8*)&As[(wid * 32 + 16 + m) * 136 + ko];
        short8 bf_[NT];
#pragma unroll
        for (int nt = 0; nt < NT; ++nt)
            bf_[nt] = *(const short8*)&Ws[(nt * 16 + m) * 136 + ko];
#pragma unroll
        for (int nt = 0; nt < NT; ++nt) {
            acc[0][nt] = __builtin_amdgcn_mfma_f32_16x16x32_bf16(af0, bf_[nt], acc[0][nt], 0, 0, 0);
            acc[1][nt] = __builtin_amdgcn_mfma_f32_16x16x32_bf16(af1, bf_[nt], acc[1][nt], 0, 0, 0);
        }
    }
    // epilogue: C layout col=lane&15, row=quad*4+i (verified layout)
#pragma unroll
    for (int rt = 0; rt < 2; ++rt)
#pragma unroll
        for (int nt = 0; nt < NT; ++nt)
#pragma unroll
            for (int i = 0; i < 4; ++i) {
                int row = r0 + wid * 32 + rt * 16 + quad * 4 + i;
                if (row < M) xw[(size_t)row * DOUT + nt * 16 + m] = f2bf(acc[rt][nt][i]);
            }
}

// ---------------- aggregation (bf16 gather): out = di*sum(dinv[s]*xw[s]) + di^2*xw[i] + b ----
template <int TPN>   // lanes per node; each lane covers 8 bf16 (16B). D = TPN*8.
__global__ __launch_bounds__(256) void agg_kernel(
    const ushort* __restrict__ xw, const float* __restrict__ dinv,
    const int* __restrict__ rowptr, const int* __restrict__ col,
    const float* __restrict__ bias, float* __restrict__ out, int n) {
    const int tid = threadIdx.x;
    const int gpb = 256 / TPN;
    const int node = blockIdx.x * gpb + tid / TPN;
    const int j = tid % TPN;
    if (node >= n) return;
    const uint4* xw4 = (const uint4*)xw;   // row pitch = TPN uint4
    const float di = dinv[node];
    const int p0 = rowptr[node], p1 = rowptr[node + 1];
    float acc[8];
#pragma unroll
    for (int i = 0; i < 8; ++i) acc[i] = 0.f;

    int p = p0;
    for (; p + 4 <= p1; p += 4) {           // 4 gathers in flight
        int s0 = col[p], s1 = col[p + 1], s2 = col[p + 2], s3 = col[p + 3];
        float w0 = dinv[s0], w1 = dinv[s1], w2 = dinv[s2], w3 = dinv[s3];
        uint4 v0 = xw4[(size_t)s0 * TPN + j];
        uint4 v1 = xw4[(size_t)s1 * TPN + j];
        uint4 v2 = xw4[(size_t)s2 * TPN + j];
        uint4 v3 = xw4[(size_t)s3 * TPN + j];
        acc[0] += w0 * bflo(v0.x); acc[1] += w0 * bfhi(v0.x);
        acc[2] += w0 * bflo(v0.y); acc[3] += w0 * bfhi(v0.y);
        acc[4] += w0 * bflo(v0.z); acc[5] += w0 * bfhi(v0.z);
        acc[6] += w0 * bflo(v0.w); acc[7] += w0 * bfhi(v0.w);
        acc[0] += w1 * bflo(v1.x); acc[1] += w1 * bfhi(v1.x);
        acc[2] += w1 * bflo(v1.y); acc[3] += w1 * bfhi(v1.y);
        acc[4] += w1 * bflo(v1.z); acc[5] += w1 * bfhi(v1.z);
        acc[6] += w1 * bflo(v1.w); acc[7] += w1 * bfhi(v1.w);
        acc[0] += w2 * bflo(v2.x); acc[1] += w2 * bfhi(v2.x);
        acc[2] += w2 * bflo(v2.y); acc[3] += w2 * bfhi(v2.y);
        acc[4] += w2 * bflo(v2.z); acc[5] += w2 * bfhi(v2.z);
        acc[6] += w2 * bflo(v2.w); acc[7] += w2 * bfhi(v2.w);
        acc[0] += w3 * bflo(v3.x); acc[1] += w3 * bfhi(v3.x);
        acc[2] += w3 * bflo(v3.y); acc[3] += w3 * bfhi(v3.y);
        acc[4] += w3 * bflo(v3.z); acc[5] += w3 * bfhi(v3.z);
        acc[6] += w3 * bflo(v3.w); acc[7] += w3 * bfhi(v3.w);
    }
    for (; p < p1; ++p) {
        int s = col[p];
        float w = dinv[s];
        uint4 v = xw4[(size_t)s * TPN + j];
        acc[0] += w * bflo(v.x); acc[1] += w * bfhi(v.x);
        acc[2] += w * bflo(v.y); acc[3] += w * bfhi(v.y);
        acc[4] += w * bflo(v.z); acc[5] += w * bfhi(v.z);
        acc[6] += w * bflo(v.w); acc[7] += w * bfhi(v.w);
    }
    uint4 vs = xw4[(size_t)node * TPN + j];
    float self[8] = { bflo(vs.x), bfhi(vs.x), bflo(vs.y), bfhi(vs.y),
                      bflo(vs.z), bfhi(vs.z), bflo(vs.w), bfhi(vs.w) };
    const float4 blo = ((const float4*)bias)[2 * j];
    const float4 bhi = ((const float4*)bias)[2 * j + 1];
    const float bb[8] = { blo.x, blo.y, blo.z, blo.w, bhi.x, bhi.y, bhi.z, bhi.w };
    const float dii = di * di;
    float o[8];
#pragma unroll
    for (int i = 0; i < 8; ++i) o[i] = di * acc[i] + dii * self[i] + bb[i];
    float* op = out + (size_t)node * (TPN * 8) + j * 8;
    ((float4*)op)[0] = make_float4(o[0], o[1], o[2], o[3]);
    ((float4*)op)[1] = make_float4(o[4], o[5], o[6], o[7]);
}

// ---------------- log_softmax over 64 classes: one wave per row ----------------
__global__ __launch_bounds__(256) void lsm_kernel(const float* __restrict__ e3,
                                                  float* __restrict__ logp, int n) {
    int row = blockIdx.x * 4 + (threadIdx.x >> 6);
    int lane = threadIdx.x & 63;
    if (row >= n) return;
    float v = e3[(size_t)row * 64 + lane];
    float m = v;
#pragma unroll
    for (int off = 32; off >= 1; off >>= 1) m = fmaxf(m, __shfl_xor(m, off, 64));
    float s = expf(v - m);
#pragma unroll
    for (int off = 32; off >= 1; off >>= 1) s += __shfl_xor(s, off, 64);
    logp[(size_t)row * 64 + lane] = v - m - logf(s);
}

// ---------------- driver ----------------
extern "C" void kernel_launch(void* const* d_in, const int* in_sizes, int n_in,
                              void* d_out, int out_size, void* d_ws, size_t ws_size,
                              hipStream_t stream) {
    const float* x  = (const float*)d_in[0];
    const void*  ei = d_in[1];
    const float* W1 = (const float*)d_in[2];
    const float* b1 = (const float*)d_in[3];
    const float* W2 = (const float*)d_in[4];
    const float* b2 = (const float*)d_in[5];
    const float* W3 = (const float*)d_in[6];
    const float* b3 = (const float*)d_in[7];
    float* out = (float*)d_out;

    const int N = in_sizes[0] / 128;   // 50000
    const int E = in_sizes[1] / 2;     // 800000

    char* w = (char*)d_ws;
    size_t off = 0;
    auto alloc = [&](size_t bytes) -> void* {
        void* p = w + off;
        off = (off + bytes + 255) & ~(size_t)255;
        return p;
    };
    int*    flag   = (int*)alloc(4);
    int*    cnt    = (int*)alloc((size_t)N * 4);
    int*    fillc  = (int*)alloc((size_t)N * 4);
    int*    rowptr = (int*)alloc((size_t)(N + 1) * 4);
    int*    bsum   = (int*)alloc(4096);
    int*    boff   = (int*)alloc(4096);
    float*  dinv   = (float*)alloc((size_t)N * 4);
    int*    col    = (int*)alloc((size_t)E * 4);
    ushort* xw     = (ushort*)alloc((size_t)N * 128 * 2);   // bf16
    ushort* Wt1    = (ushort*)alloc(16384 * 2);
    ushort* Wt2    = (ushort*)alloc(16384 * 2);
    ushort* Wt3    = (ushort*)alloc(8192 * 2);

    float* logp = out;
    float* e1 = out + (size_t)N * 64;
    float* e2 = e1 + (size_t)N * 128;
    float* e3 = e2 + (size_t)N * 128;

    const int nb = (N + 1023) / 1024;

    detect_dtype_kernel<<<1, 64, 0, stream>>>(ei, flag);
    wprep_kernel<<<160, 256, 0, stream>>>(W1, W2, W3, Wt1, Wt2, Wt3);
    zero2_kernel<<<(N + 255) / 256, 256, 0, stream>>>(cnt, fillc, N);
    hist_kernel<<<(E + 255) / 256, 256, 0, stream>>>(ei, flag, cnt, E);
    dinv_kernel<<<(N + 255) / 256, 256, 0, stream>>>(cnt, dinv, N);
    scan1_kernel<<<nb, 1024, 0, stream>>>(cnt, rowptr, bsum, N);
    scan2_kernel<<<1, 64, 0, stream>>>(bsum, boff, nb, rowptr, N, E);
    scan3_kernel<<<(N + 255) / 256, 256, 0, stream>>>(rowptr, boff, N);
    fill_kernel<<<(E + 255) / 256, 256, 0, stream>>>(ei, flag, rowptr, fillc, col, E);

    const int gblocks = (N + 127) / 128;
    // layer 1
    mfma_gemm_kernel<128><<<gblocks, 256, 0, stream>>>(x, Wt1, xw, N, 0);
    agg_kernel<16><<<(N + 15) / 16, 256, 0, stream>>>(xw, dinv, rowptr, col, b1, e1, N);
    // layer 2 (ReLU on load)
    mfma_gemm_kernel<128><<<gblocks, 256, 0, stream>>>(e1, Wt2, xw, N, 1);
    agg_kernel<16><<<(N + 15) / 16, 256, 0, stream>>>(xw, dinv, rowptr, col, b2, e2, N);
    // layer 3 (Dout=64)
    mfma_gemm_kernel<64><<<gblocks, 256, 0, stream>>>(e2, Wt3, xw, N, 1);
    agg_kernel<8><<<(N + 31) / 32, 256, 0, stream>>>(xw, dinv, rowptr, col, b3, e3, N);
    // log_softmax
    lsm_kernel<<<(N + 3) / 4, 256, 0, stream>>>(e3, logp, N);
}